// Round 2
// baseline (411.434 us; speedup 1.0000x reference)
//
#include <hip/hip_runtime.h>
#include <math.h>

// Problem constants (fixed by reference)
#define N_   32
#define CIN  32
#define COUT 16
#define D_   16
#define S_   256            // W*H
#define M_   (CIN * S_)     // 8192
#define NBLK (N_ * CIN)     // 1024 blocks = exactly 4/CU x 256 CU co-resident

#define LOG2E 1.4426950408889634f

// Partial row per (n,c,o): [0..15]=S (v-space), [16]=se, [17]=bmax, pad to 20
// floats (80 B, float4-aligned rows).
#define PROW 20
#define PIDX(n, c, o) ((((size_t)(n) * CIN + (c)) * COUT + (o)) * PROW)

// LDS tile: ls[s][16 dd], 16B chunks XOR-swizzled; conflict-free b128 reads.
#define SW(s) ((((s) & 3)) ^ (((s) >> 2) & 3))

__device__ __forceinline__ void stage_tile(const float* __restrict__ gsrc,
                                           float* ls, int tid) {
  const float4* src = (const float4*)gsrc;
#pragma unroll
  for (int j = 0; j < 4; j++) {
    int f = ((tid & 3) << 6) + (tid >> 2) + (j << 8);  // float4 index in tile
    float4 val = src[f];
    int dd = f >> 6;
    int u  = f & 63;
    int chunk = dd >> 2, lo = dd & 3;
    float vv[4] = {val.x, val.y, val.z, val.w};
#pragma unroll
    for (int m = 0; m < 4; m++) {
      int s = (u << 2) + m;
      int p = chunk ^ SW(s);
      ls[(s << 4) + (p << 2) + lo] = vv[m];
    }
  }
}

__device__ __forceinline__ void read_lp(const float* ls, int s, float* lp) {
  const float4* row = (const float4*)(ls + (s << 4));
  int sw = SW(s);
#pragma unroll
  for (int c = 0; c < 4; c++) {
    float4 q = row[c ^ sw];
    lp[c * 4 + 0] = q.x; lp[c * 4 + 1] = q.y;
    lp[c * 4 + 2] = q.z; lp[c * 4 + 3] = q.w;
  }
}

// Split dot: 4 independent fma chains.
__device__ __forceinline__ float dot16(const float* a, const float* b) {
  float a0 = 0.f, a1 = 0.f, a2 = 0.f, a3 = 0.f;
#pragma unroll
  for (int k = 0; k < 4; k++) {
    a0 = fmaf(a[k],      b[k],      a0);
    a1 = fmaf(a[4 + k],  b[4 + k],  a1);
    a2 = fmaf(a[8 + k],  b[8 + k],  a2);
    a3 = fmaf(a[12 + k], b[12 + k], a3);
  }
  return (a0 + a1) + (a2 + a3);
}

// Software grid barrier (no cooperative launch — R1 showed grid.sync was a
// silent no-op / rejected under the harness graph capture). Each barrier is a
// single-use {count, flag} int pair, zeroed by hipMemsetAsync before launch.
// Correctness across XCDs: device-scope atomics [m20] + __threadfence()
// (agent fence -> L2 writeback/invalidate). __syncthreads before arrival
// drains vmcnt, so tid0's release fence covers the whole block's stores.
// Bounded spin: a co-residency violation fails cleanly instead of hanging.
__device__ __forceinline__ void gbarrier(int* bar, int idx, int tid) {
  __syncthreads();  // all block stores issued + drained to L2
  if (tid == 0) {
    __threadfence();  // release: flush this XCD's L2
    int* cnt = bar + 2 * idx;
    int* flg = bar + 2 * idx + 1;
    if (atomicAdd(cnt, 1) == NBLK - 1) {
      __hip_atomic_store(flg, 1, __ATOMIC_RELEASE, __HIP_MEMORY_SCOPE_AGENT);
    } else {
      int guard = 0;
      while (__hip_atomic_load(flg, __ATOMIC_ACQUIRE,
                               __HIP_MEMORY_SCOPE_AGENT) == 0) {
        __builtin_amdgcn_s_sleep(8);
        if (++guard > 2000000) break;  // ~0.3 s escape: clean fail, no hang
      }
    }
    __threadfence();  // acquire: invalidate L1 + this XCD's L2
  }
  __syncthreads();
}

// One routing sweep. PASS>0: wave-0 merges the 32 per-c partials of pass-1,
// squashes, and shares dG + shift via hd. No e is kept: the final a-store
// recomputes exp2(b-shift) bitwise-identically from ls + Gacc (cheaper than
// 16 scratch-resident e_keep registers — rule #20).
template <int PASS>
__device__ __forceinline__ void routing_pass(
    int n, int c, int tid, int o, int strip,
    const float* __restrict__ wgt,
    const float* __restrict__ part_in, float* __restrict__ part_out,
    const float* ls, float red[4][18][16], float red2[18][16],
    float hd[16][20], float* Gacc, float& shift) {
  if constexpr (PASS > 0) {
    // ---- wave-0 head: merge 32 per-c partials, squash, share via LDS ----
    if (tid < 64) {
      const int ho = tid & 15, hs = tid >> 4;  // 4 c-strips x 8 c each
      float H[18];
#pragma unroll
      for (int f = 0; f < 17; f++) H[f] = 0.f;
      H[17] = -INFINITY;
#pragma unroll 2
      for (int q = 0; q < 8; q++) {
        const float* r = part_in + PIDX(n, hs + 4 * q, ho);
        const float4* r4 = (const float4*)r;
#pragma unroll
        for (int i = 0; i < 4; i++) {
          float4 v = r4[i];
          H[i * 4 + 0] += v.x; H[i * 4 + 1] += v.y;
          H[i * 4 + 2] += v.z; H[i * 4 + 3] += v.w;
        }
        H[16] += r[16];
        H[17] = fmaxf(H[17], r[17]);
      }
#pragma unroll
      for (int off = 16; off <= 32; off <<= 1) {
#pragma unroll
        for (int f = 0; f < 17; f++) H[f] += __shfl_xor(H[f], off);
        H[17] = fmaxf(H[17], __shfl_xor(H[17], off));
      }
      if (tid < 16) {  // lanes 0-15 hold full merge for o=tid
        float inv = 1.0f / H[16], n2 = 0.f, Sg[16];
#pragma unroll
        for (int d = 0; d < 16; d++) { Sg[d] = H[d] * inv; n2 = fmaf(Sg[d], Sg[d], n2); }
        float coef = n2 / ((1.f + n2) * (sqrtf(n2) + 1e-6f));
        float4* hq = (float4*)hd[tid];
#pragma unroll
        for (int i = 0; i < 4; i++)
          hq[i] = make_float4(coef * Sg[i * 4 + 0], coef * Sg[i * 4 + 1],
                              coef * Sg[i * 4 + 2], coef * Sg[i * 4 + 3]);
        hd[tid][16] = H[17];  // shift (absolute log2-domain bmax)
      }
    }
    __syncthreads();  // hd ready
    // b is linear in accumulated g: Gacc += squash-head gives accumulated b.
    const float4* hq = (const float4*)hd[o];
#pragma unroll
    for (int i = 0; i < 4; i++) {
      float4 v = hq[i];
      Gacc[i * 4 + 0] += v.x; Gacc[i * 4 + 1] += v.y;
      Gacc[i * 4 + 2] += v.z; Gacc[i * 4 + 3] += v.w;
    }
    shift = hd[o][16];
  }

  // WG[i][j] = log2e * sum_k w[j][k] * G[i][k]  (wreg loaded, then dies)
  float WG[16];
  {
    float wreg[16];
    const float4* wp = (const float4*)(wgt + (c * COUT + o) * 16);
#pragma unroll
    for (int i = 0; i < 4; i++) {
      float4 t = wp[i];
      wreg[i * 4 + 0] = t.x; wreg[i * 4 + 1] = t.y;
      wreg[i * 4 + 2] = t.z; wreg[i * 4 + 3] = t.w;
    }
#pragma unroll
    for (int i = 0; i < 4; i++)
#pragma unroll
      for (int j = 0; j < 4; j++) {
        float acc = 0.f;
#pragma unroll
        for (int k = 0; k < 4; k++)
          acc = fmaf(wreg[j * 4 + k], Gacc[i * 4 + k], acc);
        WG[i * 4 + j] = acc * LOG2E;
      }
  }

  // ---- single-phase sweep: fixed shift, plain sums (unroll 4!) ----
  float se = 0.f, bmx = -INFINITY, E[16];
#pragma unroll
  for (int d = 0; d < 16; d++) E[d] = 0.f;

#pragma unroll 4
  for (int it = 0; it < 16; it++) {
    float lp[16];
    read_lp(ls, strip + (it << 4), lp);
    float b = dot16(lp, WG) - shift;
    float e = exp2f(b);
    bmx = fmaxf(bmx, b);
    se += e;
#pragma unroll
    for (int d = 0; d < 16; d++) E[d] = fmaf(e, lp[d], E[d]);
  }

  // within-wave merge over strip bits 4,5: plain adds + fmax
#pragma unroll
  for (int off = 16; off <= 32; off <<= 1) {
    se += __shfl_xor(se, off);
    bmx = fmaxf(bmx, __shfl_xor(bmx, off));
#pragma unroll
    for (int d = 0; d < 16; d++) E[d] += __shfl_xor(E[d], off);
  }

  const int w = tid >> 6;
  if ((tid & 63) < 16) {
#pragma unroll
    for (int d = 0; d < 16; d++) red[w][d][o] = E[d];
    red[w][16][o] = se;
    red[w][17][o] = bmx;
  }
  __syncthreads();

  // cross-wave: plain 4-way sums (fmax for fld 17)
  for (int p = tid; p < 288; p += 256) {
    int f = p >> 4, oo = p & 15;
    float v0 = red[0][f][oo], v1 = red[1][f][oo];
    float v2 = red[2][f][oo], v3 = red[3][f][oo];
    red2[f][oo] = (f == 17) ? fmaxf(fmaxf(v0, v1), fmaxf(v2, v3))
                            : ((v0 + v1) + (v2 + v3));
  }
  __syncthreads();

  if (tid < 16) {  // o = tid: E -> S (v-space), vectorized partial store
    float wt[16];
    const float4* wp = (const float4*)(wgt + (c * COUT + tid) * 16);
#pragma unroll
    for (int i = 0; i < 4; i++) {
      float4 t = wp[i];
      wt[i * 4 + 0] = t.x; wt[i * 4 + 1] = t.y;
      wt[i * 4 + 2] = t.z; wt[i * 4 + 3] = t.w;
    }
    float Et[16];
#pragma unroll
    for (int d = 0; d < 16; d++) Et[d] = red2[d][tid];
    float* p0 = part_out + PIDX(n, c, tid);
    float4* p4 = (float4*)p0;
#pragma unroll
    for (int i = 0; i < 4; i++) {
      float s0 = 0.f, s1 = 0.f, s2 = 0.f, s3 = 0.f;
#pragma unroll
      for (int j = 0; j < 4; j++) {
        s0 = fmaf(Et[i * 4 + j], wt[j * 4 + 0], s0);
        s1 = fmaf(Et[i * 4 + j], wt[j * 4 + 1], s1);
        s2 = fmaf(Et[i * 4 + j], wt[j * 4 + 2], s2);
        s3 = fmaf(Et[i * 4 + j], wt[j * 4 + 3], s3);
      }
      p4[i] = make_float4(s0, s1, s2, s3);
    }
    p0[16] = red2[16][tid];
    p0[17] = red2[17][tid] + shift;  // absolute-scale bmax for next shift
  }
}

// Fully fused: 3 routing passes + normalization in ONE normal-launch kernel
// with a software grid barrier. Grid = 1024 (n,c) blocks; co-residency by
// construction: __launch_bounds__(256,4) caps VGPR at 128 (4 waves/SIMD
// exactly fills the RF), LDS 22.9 KB -> 4 blocks/CU x 256 CU = 1024.
// Wins vs 4-dispatch version:
//  - ls staged ONCE (was 3x: 2 redundant 16.8 MB global sweeps + LDS fills)
//  - Gacc carried in registers (G1 global round-trip eliminated)
//  - a_out written exactly once (a_kernel + its 33.5 MB RMW eliminated);
//    e recomputed bitwise-identically from the still-resident ls tile
//  - 3 kernel-boundary gaps replaced by ~1-2 us software barriers
__global__ __launch_bounds__(256, 4) void fused_kernel(
    const float* __restrict__ l, const float* __restrict__ wgt,
    const float* __restrict__ g0, float* __restrict__ a_out,
    float* __restrict__ g_out, float* __restrict__ PB0,
    float* __restrict__ PB1, int* __restrict__ bar) {
  const int bid = blockIdx.x;
  const int n = bid >> 5;
  const int c = bid & 31;
  const int tid = threadIdx.x;
  const int o = tid & 15;
  const int strip = tid >> 4;   // 16 s-strips

  __shared__ float ls[D_ * S_];        // 16 KB, staged once, read-only after
  __shared__ float red[4][18][16];     // 4.5 KB cross-wave buffer
  __shared__ float red2[18][16];       // 1.2 KB merged
  __shared__ float hd[16][20];         // 1.25 KB head share: dG[16], [16]=shift
  __shared__ float sinv[16];           // final 1/se per o

  stage_tile(l + ((size_t)(n * CIN + c)) * D_ * S_, ls, tid);

  float Gacc[16];
  {
    const float4* gp = (const float4*)(g0 + (n * COUT + o) * 16);
#pragma unroll
    for (int i = 0; i < 4; i++) {
      float4 u = gp[i];
      Gacc[i * 4 + 0] = u.x; Gacc[i * 4 + 1] = u.y;
      Gacc[i * 4 + 2] = u.z; Gacc[i * 4 + 3] = u.w;
    }
  }

  __syncthreads();  // tile staged

  float shift = 0.f;

  // P0: G = g0, shift 0, sweep -> PB0
  routing_pass<0>(n, c, tid, o, strip, wgt, nullptr, PB0, ls, red, red2, hd,
                  Gacc, shift);
  gbarrier(bar, 0, tid);
  // P1: Gacc += sq(head(PB0)), sweep -> PB1
  routing_pass<1>(n, c, tid, o, strip, wgt, PB0, PB1, ls, red, red2, hd,
                  Gacc, shift);
  gbarrier(bar, 1, tid);
  // P2: Gacc += sq(head(PB1)), sweep -> PB0
  routing_pass<2>(n, c, tid, o, strip, wgt, PB1, PB0, ls, red, red2, hd,
                  Gacc, shift);
  gbarrier(bar, 2, tid);

  // ---- final: inv_se per (n,o); c==0 blocks also emit g_out ----
  if (tid < 16) {
    float se = 0.f;
    if (c == 0) {
      float Ssum[16];
#pragma unroll
      for (int d = 0; d < 16; d++) Ssum[d] = 0.f;
#pragma unroll 4
      for (int cc = 0; cc < CIN; cc++) {
        const float* r = PB0 + PIDX(n, cc, tid);
        const float4* r4 = (const float4*)r;
#pragma unroll
        for (int i = 0; i < 4; i++) {
          float4 v = r4[i];
          Ssum[i * 4 + 0] += v.x; Ssum[i * 4 + 1] += v.y;
          Ssum[i * 4 + 2] += v.z; Ssum[i * 4 + 3] += v.w;
        }
        se += r[16];
      }
      float inv = 1.0f / se, n2 = 0.f;
#pragma unroll
      for (int d = 0; d < 16; d++) { Ssum[d] *= inv; n2 = fmaf(Ssum[d], Ssum[d], n2); }
      float coef = n2 / ((1.f + n2) * (sqrtf(n2) + 1e-6f));
      float* go = g_out + (n * COUT + tid) * 16;
#pragma unroll
      for (int d = 0; d < 16; d++) go[d] = coef * Ssum[d];
      sinv[tid] = inv;
    } else {
#pragma unroll 8
      for (int cc = 0; cc < CIN; cc++) se += PB0[PIDX(n, cc, tid) + 16];
      sinv[tid] = 1.0f / se;
    }
  }
  __syncthreads();

  // a = exp2(dot(lp,WG)-shift) * inv_se — recomputed bitwise-identically to
  // P2's sweep (same ls reads, same WG construction from the same Gacc, same
  // op order), so a matches e/se exactly. Stores coalesce: per it, the block
  // writes one contiguous 1 KB span (addr = tid + it*256 floats).
  float WG[16];
  {
    float wreg[16];
    const float4* wp = (const float4*)(wgt + (c * COUT + o) * 16);
#pragma unroll
    for (int i = 0; i < 4; i++) {
      float4 t = wp[i];
      wreg[i * 4 + 0] = t.x; wreg[i * 4 + 1] = t.y;
      wreg[i * 4 + 2] = t.z; wreg[i * 4 + 3] = t.w;
    }
#pragma unroll
    for (int i = 0; i < 4; i++)
#pragma unroll
      for (int j = 0; j < 4; j++) {
        float acc = 0.f;
#pragma unroll
        for (int k = 0; k < 4; k++)
          acc = fmaf(wreg[j * 4 + k], Gacc[i * 4 + k], acc);
        WG[i * 4 + j] = acc * LOG2E;
      }
  }
  const float myinv = sinv[o];
  float* abase = a_out + ((size_t)(n * M_ + c * S_)) * COUT;
#pragma unroll 4
  for (int it = 0; it < 16; it++) {
    float lp[16];
    read_lp(ls, strip + (it << 4), lp);
    float b = dot16(lp, WG) - shift;
    abase[(size_t)((strip + (it << 4)) * COUT + o)] = exp2f(b) * myinv;
  }
}

extern "C" void kernel_launch(void* const* d_in, const int* in_sizes, int n_in,
                              void* d_out, int out_size, void* d_ws, size_t ws_size,
                              hipStream_t stream) {
  const float* l = (const float*)d_in[0];
  const float* g = (const float*)d_in[1];
  const float* w = (const float*)d_in[2];
  // d_in[3] = num_iters (always 3 per setup_inputs)

  float* out = (float*)d_out;
  float* a_out = out;
  float* g_out = out + (size_t)N_ * M_ * COUT;

  float* ws = (float*)d_ws;
  float* PB0 = ws;
  float* PB1 = ws + (size_t)N_ * CIN * COUT * PROW;
  int* bar = (int*)(ws + 2 * (size_t)N_ * CIN * COUT * PROW);

  // Zero the 3 {count,flag} barrier pairs (ws is re-poisoned between runs).
  // hipMemsetAsync is graph-capturable (the harness itself uses it).
  hipMemsetAsync(bar, 0, 8 * sizeof(int), stream);

  fused_kernel<<<NBLK, 256, 0, stream>>>(l, w, g, a_out, g_out, PB0, PB1, bar);
}

// Round 3
// 269.580 us; speedup vs baseline: 1.5262x; 1.5262x over previous
//
#include <hip/hip_runtime.h>
#include <math.h>

// Problem constants (fixed by reference)
#define N_   32
#define CIN  32
#define COUT 16
#define D_   16
#define S_   256            // W*H
#define M_   (CIN * S_)     // 8192
#define NBLK (N_ * CIN)     // 1024 blocks = exactly 4/CU x 256 CU co-resident

#define LOG2E 1.4426950408889634f

// Partial row per (n,c,o): [0..15]=S (v-space), [16]=se, [17]=bmax, pad to 20
// floats (80 B, float4-aligned rows).
#define PROW 20
#define PIDX(n, c, o) ((((size_t)(n) * CIN + (c)) * COUT + (o)) * PROW)

// Barrier layout: 3 passes x 32 n, each {count @ +0, flag @ +32} in a
// 64-int (256 B) slot -> counter and flag live on DIFFERENT 128 B L2 lines,
// and different n never share a line. Total 24 KB, memset before launch.
#define BSLOT 64

// LDS tile: ls[s][16 dd], 16B chunks XOR-swizzled; conflict-free b128 reads.
#define SW(s) ((((s) & 3)) ^ (((s) >> 2) & 3))

__device__ __forceinline__ void stage_tile(const float* __restrict__ gsrc,
                                           float* ls, int tid) {
  const float4* src = (const float4*)gsrc;
#pragma unroll
  for (int j = 0; j < 4; j++) {
    int f = ((tid & 3) << 6) + (tid >> 2) + (j << 8);  // float4 index in tile
    float4 val = src[f];
    int dd = f >> 6;
    int u  = f & 63;
    int chunk = dd >> 2, lo = dd & 3;
    float vv[4] = {val.x, val.y, val.z, val.w};
#pragma unroll
    for (int m = 0; m < 4; m++) {
      int s = (u << 2) + m;
      int p = chunk ^ SW(s);
      ls[(s << 4) + (p << 2) + lo] = vv[m];
    }
  }
}

__device__ __forceinline__ void read_lp(const float* ls, int s, float* lp) {
  const float4* row = (const float4*)(ls + (s << 4));
  int sw = SW(s);
#pragma unroll
  for (int c = 0; c < 4; c++) {
    float4 q = row[c ^ sw];
    lp[c * 4 + 0] = q.x; lp[c * 4 + 1] = q.y;
    lp[c * 4 + 2] = q.z; lp[c * 4 + 3] = q.w;
  }
}

// Split dot: 4 independent fma chains.
__device__ __forceinline__ float dot16(const float* a, const float* b) {
  float a0 = 0.f, a1 = 0.f, a2 = 0.f, a3 = 0.f;
#pragma unroll
  for (int k = 0; k < 4; k++) {
    a0 = fmaf(a[k],      b[k],      a0);
    a1 = fmaf(a[4 + k],  b[4 + k],  a1);
    a2 = fmaf(a[8 + k],  b[8 + k],  a2);
    a3 = fmaf(a[12 + k], b[12 + k], a3);
  }
  return (a0 + a1) + (a2 + a3);
}

// PER-N barrier (32 blocks sharing n — the only communication group).
// R2 post-mortem: grid-wide barrier with ACQUIRE-polling cost ~80 us each:
// (a) acquire atomic load emits a full L2 buffer_inv PER POLL -> chip-wide
//     cache-pipe serialization from 1023 spinners;
// (b) 1024 atomicAdds on one cacheline serialize ~30 us at the coherence
//     point, with the polled flag on the SAME line.
// Fix: 32-arrival per-n counters on private lines; RELAXED polling (coherent-
// point read, no inv); exactly one release fence (wbL2) before arrival and
// one acquire fence (inv) after exit, per block. Bounded spin: a co-residency
// violation fails cleanly instead of hanging.
__device__ __forceinline__ void gbarrier(int* bar, int idx, int n, int tid) {
  __syncthreads();  // all block stores issued + drained
  if (tid == 0) {
    __threadfence();  // release: write back this XCD's dirty L2 lines
    int* base = bar + ((idx << 5) + n) * BSLOT;
    if (__hip_atomic_fetch_add(base, 1, __ATOMIC_RELAXED,
                               __HIP_MEMORY_SCOPE_AGENT) == CIN - 1) {
      __hip_atomic_store(base + 32, 1, __ATOMIC_RELAXED,
                         __HIP_MEMORY_SCOPE_AGENT);
    } else {
      int guard = 0;
      while (__hip_atomic_load(base + 32, __ATOMIC_RELAXED,
                               __HIP_MEMORY_SCOPE_AGENT) == 0) {
        __builtin_amdgcn_s_sleep(2);  // ~128 cy between coherent-point reads
        if (++guard > 5000000) break;  // clean fail, no hang
      }
    }
    __threadfence();  // acquire: invalidate stale L1/L2 before reading peers
  }
  __syncthreads();
}

// One routing sweep. PASS>0: wave-0 merges the 32 per-c partials of pass-1,
// squashes, and shares dG + shift via hd. No e is kept: the final a-store
// recomputes exp2(b-shift) bitwise-identically from ls + Gacc (cheaper than
// 16 scratch-resident e_keep registers — rule #20).
template <int PASS>
__device__ __forceinline__ void routing_pass(
    int n, int c, int tid, int o, int strip,
    const float* __restrict__ wgt,
    const float* __restrict__ part_in, float* __restrict__ part_out,
    const float* ls, float red[4][18][16], float red2[18][16],
    float hd[16][20], float* Gacc, float& shift) {
  if constexpr (PASS > 0) {
    // ---- wave-0 head: merge 32 per-c partials, squash, share via LDS ----
    if (tid < 64) {
      const int ho = tid & 15, hs = tid >> 4;  // 4 c-strips x 8 c each
      float H[18];
#pragma unroll
      for (int f = 0; f < 17; f++) H[f] = 0.f;
      H[17] = -INFINITY;
#pragma unroll 2
      for (int q = 0; q < 8; q++) {
        const float* r = part_in + PIDX(n, hs + 4 * q, ho);
        const float4* r4 = (const float4*)r;
#pragma unroll
        for (int i = 0; i < 4; i++) {
          float4 v = r4[i];
          H[i * 4 + 0] += v.x; H[i * 4 + 1] += v.y;
          H[i * 4 + 2] += v.z; H[i * 4 + 3] += v.w;
        }
        H[16] += r[16];
        H[17] = fmaxf(H[17], r[17]);
      }
#pragma unroll
      for (int off = 16; off <= 32; off <<= 1) {
#pragma unroll
        for (int f = 0; f < 17; f++) H[f] += __shfl_xor(H[f], off);
        H[17] = fmaxf(H[17], __shfl_xor(H[17], off));
      }
      if (tid < 16) {  // lanes 0-15 hold full merge for o=tid
        float inv = 1.0f / H[16], n2 = 0.f, Sg[16];
#pragma unroll
        for (int d = 0; d < 16; d++) { Sg[d] = H[d] * inv; n2 = fmaf(Sg[d], Sg[d], n2); }
        float coef = n2 / ((1.f + n2) * (sqrtf(n2) + 1e-6f));
        float4* hq = (float4*)hd[tid];
#pragma unroll
        for (int i = 0; i < 4; i++)
          hq[i] = make_float4(coef * Sg[i * 4 + 0], coef * Sg[i * 4 + 1],
                              coef * Sg[i * 4 + 2], coef * Sg[i * 4 + 3]);
        hd[tid][16] = H[17];  // shift (absolute log2-domain bmax)
      }
    }
    __syncthreads();  // hd ready
    // b is linear in accumulated g: Gacc += squash-head gives accumulated b.
    const float4* hq = (const float4*)hd[o];
#pragma unroll
    for (int i = 0; i < 4; i++) {
      float4 v = hq[i];
      Gacc[i * 4 + 0] += v.x; Gacc[i * 4 + 1] += v.y;
      Gacc[i * 4 + 2] += v.z; Gacc[i * 4 + 3] += v.w;
    }
    shift = hd[o][16];
  }

  // WG[i][j] = log2e * sum_k w[j][k] * G[i][k]  (wreg loaded, then dies)
  float WG[16];
  {
    float wreg[16];
    const float4* wp = (const float4*)(wgt + (c * COUT + o) * 16);
#pragma unroll
    for (int i = 0; i < 4; i++) {
      float4 t = wp[i];
      wreg[i * 4 + 0] = t.x; wreg[i * 4 + 1] = t.y;
      wreg[i * 4 + 2] = t.z; wreg[i * 4 + 3] = t.w;
    }
#pragma unroll
    for (int i = 0; i < 4; i++)
#pragma unroll
      for (int j = 0; j < 4; j++) {
        float acc = 0.f;
#pragma unroll
        for (int k = 0; k < 4; k++)
          acc = fmaf(wreg[j * 4 + k], Gacc[i * 4 + k], acc);
        WG[i * 4 + j] = acc * LOG2E;
      }
  }

  // ---- single-phase sweep: fixed shift, plain sums (unroll 4!) ----
  float se = 0.f, bmx = -INFINITY, E[16];
#pragma unroll
  for (int d = 0; d < 16; d++) E[d] = 0.f;

#pragma unroll 4
  for (int it = 0; it < 16; it++) {
    float lp[16];
    read_lp(ls, strip + (it << 4), lp);
    float b = dot16(lp, WG) - shift;
    float e = exp2f(b);
    bmx = fmaxf(bmx, b);
    se += e;
#pragma unroll
    for (int d = 0; d < 16; d++) E[d] = fmaf(e, lp[d], E[d]);
  }

  // within-wave merge over strip bits 4,5: plain adds + fmax
#pragma unroll
  for (int off = 16; off <= 32; off <<= 1) {
    se += __shfl_xor(se, off);
    bmx = fmaxf(bmx, __shfl_xor(bmx, off));
#pragma unroll
    for (int d = 0; d < 16; d++) E[d] += __shfl_xor(E[d], off);
  }

  const int w = tid >> 6;
  if ((tid & 63) < 16) {
#pragma unroll
    for (int d = 0; d < 16; d++) red[w][d][o] = E[d];
    red[w][16][o] = se;
    red[w][17][o] = bmx;
  }
  __syncthreads();

  // cross-wave: plain 4-way sums (fmax for fld 17)
  for (int p = tid; p < 288; p += 256) {
    int f = p >> 4, oo = p & 15;
    float v0 = red[0][f][oo], v1 = red[1][f][oo];
    float v2 = red[2][f][oo], v3 = red[3][f][oo];
    red2[f][oo] = (f == 17) ? fmaxf(fmaxf(v0, v1), fmaxf(v2, v3))
                            : ((v0 + v1) + (v2 + v3));
  }
  __syncthreads();

  if (tid < 16) {  // o = tid: E -> S (v-space), vectorized partial store
    float wt[16];
    const float4* wp = (const float4*)(wgt + (c * COUT + tid) * 16);
#pragma unroll
    for (int i = 0; i < 4; i++) {
      float4 t = wp[i];
      wt[i * 4 + 0] = t.x; wt[i * 4 + 1] = t.y;
      wt[i * 4 + 2] = t.z; wt[i * 4 + 3] = t.w;
    }
    float Et[16];
#pragma unroll
    for (int d = 0; d < 16; d++) Et[d] = red2[d][tid];
    float* p0 = part_out + PIDX(n, c, tid);
    float4* p4 = (float4*)p0;
#pragma unroll
    for (int i = 0; i < 4; i++) {
      float s0 = 0.f, s1 = 0.f, s2 = 0.f, s3 = 0.f;
#pragma unroll
      for (int j = 0; j < 4; j++) {
        s0 = fmaf(Et[i * 4 + j], wt[j * 4 + 0], s0);
        s1 = fmaf(Et[i * 4 + j], wt[j * 4 + 1], s1);
        s2 = fmaf(Et[i * 4 + j], wt[j * 4 + 2], s2);
        s3 = fmaf(Et[i * 4 + j], wt[j * 4 + 3], s3);
      }
      p4[i] = make_float4(s0, s1, s2, s3);
    }
    p0[16] = red2[16][tid];
    p0[17] = red2[17][tid] + shift;  // absolute-scale bmax for next shift
  }
}

// Fully fused: 3 routing passes + normalization in ONE normal-launch kernel
// with PER-N software barriers (32 blocks each — the true comm group).
// Grid = 1024 (n,c) blocks; co-residency by construction:
// __launch_bounds__(256,4) (VGPR 60 measured), LDS 22.9 KB -> 4 blocks/CU.
__global__ __launch_bounds__(256, 4) void fused_kernel(
    const float* __restrict__ l, const float* __restrict__ wgt,
    const float* __restrict__ g0, float* __restrict__ a_out,
    float* __restrict__ g_out, float* __restrict__ PB0,
    float* __restrict__ PB1, int* __restrict__ bar) {
  const int bid = blockIdx.x;
  const int n = bid >> 5;
  const int c = bid & 31;
  const int tid = threadIdx.x;
  const int o = tid & 15;
  const int strip = tid >> 4;   // 16 s-strips

  __shared__ float ls[D_ * S_];        // 16 KB, staged once, read-only after
  __shared__ float red[4][18][16];     // 4.5 KB cross-wave buffer
  __shared__ float red2[18][16];       // 1.2 KB merged
  __shared__ float hd[16][20];         // 1.25 KB head share: dG[16], [16]=shift
  __shared__ float sinv[16];           // final 1/se per o

  stage_tile(l + ((size_t)(n * CIN + c)) * D_ * S_, ls, tid);

  float Gacc[16];
  {
    const float4* gp = (const float4*)(g0 + (n * COUT + o) * 16);
#pragma unroll
    for (int i = 0; i < 4; i++) {
      float4 u = gp[i];
      Gacc[i * 4 + 0] = u.x; Gacc[i * 4 + 1] = u.y;
      Gacc[i * 4 + 2] = u.z; Gacc[i * 4 + 3] = u.w;
    }
  }

  __syncthreads();  // tile staged

  float shift = 0.f;

  // P0: G = g0, shift 0, sweep -> PB0
  routing_pass<0>(n, c, tid, o, strip, wgt, nullptr, PB0, ls, red, red2, hd,
                  Gacc, shift);
  gbarrier(bar, 0, n, tid);
  // P1: Gacc += sq(head(PB0)), sweep -> PB1
  routing_pass<1>(n, c, tid, o, strip, wgt, PB0, PB1, ls, red, red2, hd,
                  Gacc, shift);
  gbarrier(bar, 1, n, tid);
  // P2: Gacc += sq(head(PB1)), sweep -> PB0
  routing_pass<2>(n, c, tid, o, strip, wgt, PB1, PB0, ls, red, red2, hd,
                  Gacc, shift);
  gbarrier(bar, 2, n, tid);

  // ---- final: inv_se per (n,o); c==0 blocks also emit g_out ----
  if (tid < 16) {
    float se = 0.f;
    if (c == 0) {
      float Ssum[16];
#pragma unroll
      for (int d = 0; d < 16; d++) Ssum[d] = 0.f;
#pragma unroll 4
      for (int cc = 0; cc < CIN; cc++) {
        const float* r = PB0 + PIDX(n, cc, tid);
        const float4* r4 = (const float4*)r;
#pragma unroll
        for (int i = 0; i < 4; i++) {
          float4 v = r4[i];
          Ssum[i * 4 + 0] += v.x; Ssum[i * 4 + 1] += v.y;
          Ssum[i * 4 + 2] += v.z; Ssum[i * 4 + 3] += v.w;
        }
        se += r[16];
      }
      float inv = 1.0f / se, n2 = 0.f;
#pragma unroll
      for (int d = 0; d < 16; d++) { Ssum[d] *= inv; n2 = fmaf(Ssum[d], Ssum[d], n2); }
      float coef = n2 / ((1.f + n2) * (sqrtf(n2) + 1e-6f));
      float* go = g_out + (n * COUT + tid) * 16;
#pragma unroll
      for (int d = 0; d < 16; d++) go[d] = coef * Ssum[d];
      sinv[tid] = inv;
    } else {
#pragma unroll 8
      for (int cc = 0; cc < CIN; cc++) se += PB0[PIDX(n, cc, tid) + 16];
      sinv[tid] = 1.0f / se;
    }
  }
  __syncthreads();

  // a = exp2(dot(lp,WG)-shift) * inv_se — recomputed bitwise-identically to
  // P2's sweep (same ls reads, same WG construction from the same Gacc, same
  // op order), so a matches e/se exactly. Stores coalesce: per it, the block
  // writes one contiguous 1 KB span (addr = tid + it*256 floats).
  float WG[16];
  {
    float wreg[16];
    const float4* wp = (const float4*)(wgt + (c * COUT + o) * 16);
#pragma unroll
    for (int i = 0; i < 4; i++) {
      float4 t = wp[i];
      wreg[i * 4 + 0] = t.x; wreg[i * 4 + 1] = t.y;
      wreg[i * 4 + 2] = t.z; wreg[i * 4 + 3] = t.w;
    }
#pragma unroll
    for (int i = 0; i < 4; i++)
#pragma unroll
      for (int j = 0; j < 4; j++) {
        float acc = 0.f;
#pragma unroll
        for (int k = 0; k < 4; k++)
          acc = fmaf(wreg[j * 4 + k], Gacc[i * 4 + k], acc);
        WG[i * 4 + j] = acc * LOG2E;
      }
  }
  const float myinv = sinv[o];
  float* abase = a_out + ((size_t)(n * M_ + c * S_)) * COUT;
#pragma unroll 4
  for (int it = 0; it < 16; it++) {
    float lp[16];
    read_lp(ls, strip + (it << 4), lp);
    float b = dot16(lp, WG) - shift;
    abase[(size_t)((strip + (it << 4)) * COUT + o)] = exp2f(b) * myinv;
  }
}

extern "C" void kernel_launch(void* const* d_in, const int* in_sizes, int n_in,
                              void* d_out, int out_size, void* d_ws, size_t ws_size,
                              hipStream_t stream) {
  const float* l = (const float*)d_in[0];
  const float* g = (const float*)d_in[1];
  const float* w = (const float*)d_in[2];
  // d_in[3] = num_iters (always 3 per setup_inputs)

  float* out = (float*)d_out;
  float* a_out = out;
  float* g_out = out + (size_t)N_ * M_ * COUT;

  float* ws = (float*)d_ws;
  float* PB0 = ws;
  float* PB1 = ws + (size_t)N_ * CIN * COUT * PROW;
  int* bar = (int*)(ws + 2 * (size_t)N_ * CIN * COUT * PROW);

  // Zero the 3x32 per-n {count,flag} barrier slots (ws is re-poisoned
  // between runs). hipMemsetAsync is graph-capturable.
  hipMemsetAsync(bar, 0, 3 * N_ * BSLOT * sizeof(int), stream);

  fused_kernel<<<NBLK, 256, 0, stream>>>(l, w, g, a_out, g_out, PB0, PB1, bar);
}

// Round 4
// 124.237 us; speedup vs baseline: 3.3117x; 2.1699x over previous
//
#include <hip/hip_runtime.h>
#include <math.h>

// Problem constants (fixed by reference)
#define N_   32
#define CIN  32
#define COUT 16
#define D_   16
#define S_   256            // W*H
#define M_   (CIN * S_)     // 8192
#define NBLK (N_ * CIN)     // 1024 blocks = exactly 4/CU x 256 CU co-resident

#define LOG2E 1.4426950408889634f

// Partial row per (n,c,o): [0..15]=S (v-space), [16]=se, [17]=bmax, pad to 20
// floats (80 B, 8 B-aligned rows for the atomic 8-byte packs).
#define PROW 20
#define PIDX(n, c, o) ((((size_t)(n) * CIN + (c)) * COUT + (o)) * PROW)

// Barrier layout: 3 passes x 32 n, each {count @ +0, flag @ +32} in a
// 64-int (256 B) slot -> counter and flag on different 128 B lines.
#define BSLOT 64

// ---- coherence-point (cache-bypass, sc1) 8-byte data movement ----
// R3 post-mortem: the per-barrier __threadfence() pair (buffer_wbl2 +
// buffer_inv = full 4 MiB L2 walk, 6144 of them) was ~55 us/barrier.
// Instead, all cross-block-communicated data uses RELAXED AGENT atomics,
// which on gfx950 compile to sc1 cache-bypassing ops (proven by R3's spin
// loop observing cross-XCD flags with no invalidates). Write-through stores
// never dirty L2; bypass loads never read stale L2 -> no fences needed.
__device__ __forceinline__ float2 aload_f2(const float* p) {
  unsigned long long v = __hip_atomic_load(
      (const unsigned long long*)p, __ATOMIC_RELAXED, __HIP_MEMORY_SCOPE_AGENT);
  float2 r;
  r.x = __uint_as_float((unsigned)v);
  r.y = __uint_as_float((unsigned)(v >> 32));
  return r;
}
__device__ __forceinline__ void astore_f2(float* p, float a, float b) {
  unsigned long long v =
      ((unsigned long long)__float_as_uint(b) << 32) | __float_as_uint(a);
  __hip_atomic_store((unsigned long long*)p, v, __ATOMIC_RELAXED,
                     __HIP_MEMORY_SCOPE_AGENT);
}

// LDS tile: ls[s][16 dd], 16B chunks XOR-swizzled; conflict-free b128 reads.
#define SW(s) ((((s) & 3)) ^ (((s) >> 2) & 3))

__device__ __forceinline__ void stage_tile(const float* __restrict__ gsrc,
                                           float* ls, int tid) {
  const float4* src = (const float4*)gsrc;
#pragma unroll
  for (int j = 0; j < 4; j++) {
    int f = ((tid & 3) << 6) + (tid >> 2) + (j << 8);  // float4 index in tile
    float4 val = src[f];
    int dd = f >> 6;
    int u  = f & 63;
    int chunk = dd >> 2, lo = dd & 3;
    float vv[4] = {val.x, val.y, val.z, val.w};
#pragma unroll
    for (int m = 0; m < 4; m++) {
      int s = (u << 2) + m;
      int p = chunk ^ SW(s);
      ls[(s << 4) + (p << 2) + lo] = vv[m];
    }
  }
}

__device__ __forceinline__ void read_lp(const float* ls, int s, float* lp) {
  const float4* row = (const float4*)(ls + (s << 4));
  int sw = SW(s);
#pragma unroll
  for (int c = 0; c < 4; c++) {
    float4 q = row[c ^ sw];
    lp[c * 4 + 0] = q.x; lp[c * 4 + 1] = q.y;
    lp[c * 4 + 2] = q.z; lp[c * 4 + 3] = q.w;
  }
}

// Split dot: 4 independent fma chains.
__device__ __forceinline__ float dot16(const float* a, const float* b) {
  float a0 = 0.f, a1 = 0.f, a2 = 0.f, a3 = 0.f;
#pragma unroll
  for (int k = 0; k < 4; k++) {
    a0 = fmaf(a[k],      b[k],      a0);
    a1 = fmaf(a[4 + k],  b[4 + k],  a1);
    a2 = fmaf(a[8 + k],  b[8 + k],  a2);
    a3 = fmaf(a[12 + k], b[12 + k], a3);
  }
  return (a0 + a1) + (a2 + a3);
}

// PER-N barrier, FENCE-FREE. Ordering argument:
//  writer: sc1 data stores -> __syncthreads (per-wave s_waitcnt vmcnt(0) =
//          stores acked at the coherence point) -> relaxed atomicAdd at the
//          SAME coherence point => globally ordered after the data.
//  reader: sees flag -> subsequent sc1 loads read the coherence point
//          directly => cannot return pre-flag data. No L2 flush/inv anywhere.
// Bounded spin: a co-residency violation fails cleanly instead of hanging.
__device__ __forceinline__ void gbarrier(int* bar, int idx, int n, int tid) {
  __syncthreads();  // all block stores issued + vmcnt-drained
  if (tid == 0) {
    int* base = bar + ((idx << 5) + n) * BSLOT;
    if (__hip_atomic_fetch_add(base, 1, __ATOMIC_RELAXED,
                               __HIP_MEMORY_SCOPE_AGENT) == CIN - 1) {
      __hip_atomic_store(base + 32, 1, __ATOMIC_RELAXED,
                         __HIP_MEMORY_SCOPE_AGENT);
    } else {
      int guard = 0;
      while (__hip_atomic_load(base + 32, __ATOMIC_RELAXED,
                               __HIP_MEMORY_SCOPE_AGENT) == 0) {
        __builtin_amdgcn_s_sleep(2);  // ~128 cy between coherent-point reads
        if (++guard > 5000000) break;  // clean fail, no hang
      }
    }
  }
  __syncthreads();
}

// One routing sweep. PASS>0: wave-0 merges the 32 per-c partials of pass-1,
// squashes, and shares dG + shift via hd. No e is kept: the final a-store
// recomputes exp2(b-shift) bitwise-identically from ls + Gacc.
template <int PASS>
__device__ __forceinline__ void routing_pass(
    int n, int c, int tid, int o, int strip,
    const float* __restrict__ wgt,
    const float* __restrict__ part_in, float* __restrict__ part_out,
    const float* ls, float red[4][18][16], float red2[18][16],
    float hd[16][20], float* Gacc, float& shift) {
  if constexpr (PASS > 0) {
    // ---- wave-0 head: merge 32 per-c partials, squash, share via LDS ----
    if (tid < 64) {
      const int ho = tid & 15, hs = tid >> 4;  // 4 c-strips x 8 c each
      float H[18];
#pragma unroll
      for (int f = 0; f < 17; f++) H[f] = 0.f;
      H[17] = -INFINITY;
#pragma unroll 2
      for (int q = 0; q < 8; q++) {
        const float* r = part_in + PIDX(n, hs + 4 * q, ho);
#pragma unroll
        for (int i = 0; i < 8; i++) {
          float2 v = aload_f2(r + 2 * i);  // coherence-point read
          H[2 * i + 0] += v.x;
          H[2 * i + 1] += v.y;
        }
        float2 t = aload_f2(r + 16);
        H[16] += t.x;
        H[17] = fmaxf(H[17], t.y);
      }
#pragma unroll
      for (int off = 16; off <= 32; off <<= 1) {
#pragma unroll
        for (int f = 0; f < 17; f++) H[f] += __shfl_xor(H[f], off);
        H[17] = fmaxf(H[17], __shfl_xor(H[17], off));
      }
      if (tid < 16) {  // lanes 0-15 hold full merge for o=tid
        float inv = 1.0f / H[16], n2 = 0.f, Sg[16];
#pragma unroll
        for (int d = 0; d < 16; d++) { Sg[d] = H[d] * inv; n2 = fmaf(Sg[d], Sg[d], n2); }
        float coef = n2 / ((1.f + n2) * (sqrtf(n2) + 1e-6f));
        float4* hq = (float4*)hd[tid];
#pragma unroll
        for (int i = 0; i < 4; i++)
          hq[i] = make_float4(coef * Sg[i * 4 + 0], coef * Sg[i * 4 + 1],
                              coef * Sg[i * 4 + 2], coef * Sg[i * 4 + 3]);
        hd[tid][16] = H[17];  // shift (absolute log2-domain bmax)
      }
    }
    __syncthreads();  // hd ready
    // b is linear in accumulated g: Gacc += squash-head gives accumulated b.
    const float4* hq = (const float4*)hd[o];
#pragma unroll
    for (int i = 0; i < 4; i++) {
      float4 v = hq[i];
      Gacc[i * 4 + 0] += v.x; Gacc[i * 4 + 1] += v.y;
      Gacc[i * 4 + 2] += v.z; Gacc[i * 4 + 3] += v.w;
    }
    shift = hd[o][16];
  }

  // WG[i][j] = log2e * sum_k w[j][k] * G[i][k]  (wreg loaded, then dies)
  float WG[16];
  {
    float wreg[16];
    const float4* wp = (const float4*)(wgt + (c * COUT + o) * 16);
#pragma unroll
    for (int i = 0; i < 4; i++) {
      float4 t = wp[i];
      wreg[i * 4 + 0] = t.x; wreg[i * 4 + 1] = t.y;
      wreg[i * 4 + 2] = t.z; wreg[i * 4 + 3] = t.w;
    }
#pragma unroll
    for (int i = 0; i < 4; i++)
#pragma unroll
      for (int j = 0; j < 4; j++) {
        float acc = 0.f;
#pragma unroll
        for (int k = 0; k < 4; k++)
          acc = fmaf(wreg[j * 4 + k], Gacc[i * 4 + k], acc);
        WG[i * 4 + j] = acc * LOG2E;
      }
  }

  // ---- single-phase sweep: fixed shift, plain sums (unroll 4!) ----
  float se = 0.f, bmx = -INFINITY, E[16];
#pragma unroll
  for (int d = 0; d < 16; d++) E[d] = 0.f;

#pragma unroll 4
  for (int it = 0; it < 16; it++) {
    float lp[16];
    read_lp(ls, strip + (it << 4), lp);
    float b = dot16(lp, WG) - shift;
    float e = exp2f(b);
    bmx = fmaxf(bmx, b);
    se += e;
#pragma unroll
    for (int d = 0; d < 16; d++) E[d] = fmaf(e, lp[d], E[d]);
  }

  // within-wave merge over strip bits 4,5: plain adds + fmax
#pragma unroll
  for (int off = 16; off <= 32; off <<= 1) {
    se += __shfl_xor(se, off);
    bmx = fmaxf(bmx, __shfl_xor(bmx, off));
#pragma unroll
    for (int d = 0; d < 16; d++) E[d] += __shfl_xor(E[d], off);
  }

  const int w = tid >> 6;
  if ((tid & 63) < 16) {
#pragma unroll
    for (int d = 0; d < 16; d++) red[w][d][o] = E[d];
    red[w][16][o] = se;
    red[w][17][o] = bmx;
  }
  __syncthreads();

  // cross-wave: plain 4-way sums (fmax for fld 17)
  for (int p = tid; p < 288; p += 256) {
    int f = p >> 4, oo = p & 15;
    float v0 = red[0][f][oo], v1 = red[1][f][oo];
    float v2 = red[2][f][oo], v3 = red[3][f][oo];
    red2[f][oo] = (f == 17) ? fmaxf(fmaxf(v0, v1), fmaxf(v2, v3))
                            : ((v0 + v1) + (v2 + v3));
  }
  __syncthreads();

  if (tid < 16) {  // o = tid: E -> S (v-space), coherence-point store
    float wt[16];
    const float4* wp = (const float4*)(wgt + (c * COUT + tid) * 16);
#pragma unroll
    for (int i = 0; i < 4; i++) {
      float4 t = wp[i];
      wt[i * 4 + 0] = t.x; wt[i * 4 + 1] = t.y;
      wt[i * 4 + 2] = t.z; wt[i * 4 + 3] = t.w;
    }
    float Et[16];
#pragma unroll
    for (int d = 0; d < 16; d++) Et[d] = red2[d][tid];
    float* p0 = part_out + PIDX(n, c, tid);
#pragma unroll
    for (int i = 0; i < 4; i++) {
      float s0 = 0.f, s1 = 0.f, s2 = 0.f, s3 = 0.f;
#pragma unroll
      for (int j = 0; j < 4; j++) {
        s0 = fmaf(Et[i * 4 + j], wt[j * 4 + 0], s0);
        s1 = fmaf(Et[i * 4 + j], wt[j * 4 + 1], s1);
        s2 = fmaf(Et[i * 4 + j], wt[j * 4 + 2], s2);
        s3 = fmaf(Et[i * 4 + j], wt[j * 4 + 3], s3);
      }
      astore_f2(p0 + 4 * i + 0, s0, s1);  // write-through sc1: never dirty
      astore_f2(p0 + 4 * i + 2, s2, s3);
    }
    astore_f2(p0 + 16, red2[16][tid], red2[17][tid] + shift);
  }
}

// Fully fused: 3 routing passes + normalization in ONE normal-launch kernel
// with FENCE-FREE per-n software barriers; all cross-block data moves via
// sc1 coherence-point atomics. Grid = 1024 (n,c) blocks; co-residency by
// construction: __launch_bounds__(256,4), LDS 22.9 KB -> 4 blocks/CU.
__global__ __launch_bounds__(256, 4) void fused_kernel(
    const float* __restrict__ l, const float* __restrict__ wgt,
    const float* __restrict__ g0, float* __restrict__ a_out,
    float* __restrict__ g_out, float* __restrict__ PB0,
    float* __restrict__ PB1, int* __restrict__ bar) {
  const int bid = blockIdx.x;
  const int n = bid >> 5;
  const int c = bid & 31;
  const int tid = threadIdx.x;
  const int o = tid & 15;
  const int strip = tid >> 4;   // 16 s-strips

  __shared__ float ls[D_ * S_];        // 16 KB, staged once, read-only after
  __shared__ float red[4][18][16];     // 4.5 KB cross-wave buffer
  __shared__ float red2[18][16];       // 1.2 KB merged
  __shared__ float hd[16][20];         // 1.25 KB head share: dG[16], [16]=shift
  __shared__ float sinv[16];           // final 1/se per o

  stage_tile(l + ((size_t)(n * CIN + c)) * D_ * S_, ls, tid);

  float Gacc[16];
  {
    const float4* gp = (const float4*)(g0 + (n * COUT + o) * 16);
#pragma unroll
    for (int i = 0; i < 4; i++) {
      float4 u = gp[i];
      Gacc[i * 4 + 0] = u.x; Gacc[i * 4 + 1] = u.y;
      Gacc[i * 4 + 2] = u.z; Gacc[i * 4 + 3] = u.w;
    }
  }

  __syncthreads();  // tile staged

  float shift = 0.f;

  // P0: G = g0, shift 0, sweep -> PB0
  routing_pass<0>(n, c, tid, o, strip, wgt, nullptr, PB0, ls, red, red2, hd,
                  Gacc, shift);
  gbarrier(bar, 0, n, tid);
  // P1: Gacc += sq(head(PB0)), sweep -> PB1
  routing_pass<1>(n, c, tid, o, strip, wgt, PB0, PB1, ls, red, red2, hd,
                  Gacc, shift);
  gbarrier(bar, 1, n, tid);
  // P2: Gacc += sq(head(PB1)), sweep -> PB0
  routing_pass<2>(n, c, tid, o, strip, wgt, PB1, PB0, ls, red, red2, hd,
                  Gacc, shift);
  gbarrier(bar, 2, n, tid);

  // ---- final: inv_se per (n,o); c==0 blocks also emit g_out ----
  if (tid < 16) {
    float se = 0.f;
    if (c == 0) {
      float Ssum[16];
#pragma unroll
      for (int d = 0; d < 16; d++) Ssum[d] = 0.f;
#pragma unroll 4
      for (int cc = 0; cc < CIN; cc++) {
        const float* r = PB0 + PIDX(n, cc, tid);
#pragma unroll
        for (int i = 0; i < 8; i++) {
          float2 v = aload_f2(r + 2 * i);
          Ssum[2 * i + 0] += v.x;
          Ssum[2 * i + 1] += v.y;
        }
        se += aload_f2(r + 16).x;
      }
      float inv = 1.0f / se, n2 = 0.f;
#pragma unroll
      for (int d = 0; d < 16; d++) { Ssum[d] *= inv; n2 = fmaf(Ssum[d], Ssum[d], n2); }
      float coef = n2 / ((1.f + n2) * (sqrtf(n2) + 1e-6f));
      float* go = g_out + (n * COUT + tid) * 16;
#pragma unroll
      for (int d = 0; d < 16; d++) go[d] = coef * Ssum[d];
      sinv[tid] = inv;
    } else {
#pragma unroll 8
      for (int cc = 0; cc < CIN; cc++)
        se += aload_f2(PB0 + PIDX(n, cc, tid) + 16).x;
      sinv[tid] = 1.0f / se;
    }
  }
  __syncthreads();

  // a = exp2(dot(lp,WG)-shift) * inv_se — recomputed bitwise-identically to
  // P2's sweep (same ls reads, same WG construction from the same Gacc, same
  // op order), so a matches e/se exactly. Stores coalesce: per it, the block
  // writes one contiguous 1 KB span (addr = tid + it*256 floats).
  float WG[16];
  {
    float wreg[16];
    const float4* wp = (const float4*)(wgt + (c * COUT + o) * 16);
#pragma unroll
    for (int i = 0; i < 4; i++) {
      float4 t = wp[i];
      wreg[i * 4 + 0] = t.x; wreg[i * 4 + 1] = t.y;
      wreg[i * 4 + 2] = t.z; wreg[i * 4 + 3] = t.w;
    }
#pragma unroll
    for (int i = 0; i < 4; i++)
#pragma unroll
      for (int j = 0; j < 4; j++) {
        float acc = 0.f;
#pragma unroll
        for (int k = 0; k < 4; k++)
          acc = fmaf(wreg[j * 4 + k], Gacc[i * 4 + k], acc);
        WG[i * 4 + j] = acc * LOG2E;
      }
  }
  const float myinv = sinv[o];
  float* abase = a_out + ((size_t)(n * M_ + c * S_)) * COUT;
#pragma unroll 4
  for (int it = 0; it < 16; it++) {
    float lp[16];
    read_lp(ls, strip + (it << 4), lp);
    float b = dot16(lp, WG) - shift;
    abase[(size_t)((strip + (it << 4)) * COUT + o)] = exp2f(b) * myinv;
  }
}

extern "C" void kernel_launch(void* const* d_in, const int* in_sizes, int n_in,
                              void* d_out, int out_size, void* d_ws, size_t ws_size,
                              hipStream_t stream) {
  const float* l = (const float*)d_in[0];
  const float* g = (const float*)d_in[1];
  const float* w = (const float*)d_in[2];
  // d_in[3] = num_iters (always 3 per setup_inputs)

  float* out = (float*)d_out;
  float* a_out = out;
  float* g_out = out + (size_t)N_ * M_ * COUT;

  float* ws = (float*)d_ws;
  float* PB0 = ws;
  float* PB1 = ws + (size_t)N_ * CIN * COUT * PROW;
  int* bar = (int*)(ws + 2 * (size_t)N_ * CIN * COUT * PROW);

  // Zero the 3x32 per-n {count,flag} barrier slots (ws is re-poisoned
  // between runs). hipMemsetAsync is graph-capturable.
  hipMemsetAsync(bar, 0, 3 * N_ * BSLOT * sizeof(int), stream);

  fused_kernel<<<NBLK, 256, 0, stream>>>(l, w, g, a_out, g_out, PB0, PB1, bar);
}